// Round 9
// baseline (874.044 us; speedup 1.0000x reference)
//
#include <hip/hip_runtime.h>

#define NN 100000
#define NE 1600000
#define NF 128
#define NH 64
#define NK 20
#define SBK 192                     // nodes per bucket (LDS acc tile)
#define NSB ((NN + SBK - 1) / SBK)  // 521 buckets
#define CT 4096                     // edges per coarse-scatter block
#define AGW 8                       // waves in k_agg block (512 threads)

static constexpr float ALPHA = 0.2f;

typedef unsigned short u16;
typedef unsigned int u32;

// ---- workspace layout (aligned to 256B) ----
constexpr size_t alup(size_t x) { return (x + 255) & ~size_t(255); }
constexpr size_t O_FLAG   = 0;                                    // 4 B
constexpr size_t O_DINV   = 256;                                  // NN f32
constexpr size_t O_GBH    = alup(O_DINV + size_t(NN) * 4);        // NSB i32 (bucket edge counts)
constexpr size_t O_BBASE  = alup(O_GBH  + size_t(NSB) * 4);       // NSB+1 i32
constexpr size_t O_BCUR   = alup(O_BBASE + size_t(NSB + 1) * 4);  // NSB i32
constexpr size_t O_COARSE = alup(O_BCUR + size_t(NSB) * 4);       // NE uint2 (12.8 MB) bucket-grouped
constexpr size_t O_SUP    = alup(O_COARSE + size_t(NE) * 8);      // NN*NH bf16 (12.8 MB), dinv-scaled x@W
// total ~ 26 MB

__device__ __forceinline__ u16 f2bf(float f) {   // RNE float->bf16
  u32 u = __float_as_uint(f);
  u32 r = (u + 0x7fffu + ((u >> 16) & 1u)) >> 16;
  return (u16)r;
}
__device__ __forceinline__ float bf2f(u16 h) {
  return __uint_as_float(((u32)h) << 16);
}

// edge_index dtype probe + zero the bucket histogram.
__global__ __launch_bounds__(256) void k_detect(const void* ei, int* flag, int* gbh) {
  __shared__ int bad;
  if (threadIdx.x == 0) bad = 0;
  for (int i = threadIdx.x; i < NSB; i += 256) gbh[i] = 0;
  __syncthreads();
  const long long* p = (const long long*)ei;
  int ok = 1;
#pragma unroll
  for (int k = 0; k < 4; ++k) {
    long long v = p[threadIdx.x * 4 + k];
    if (v < 0 || v >= NN) ok = 0;
  }
  if (!ok) atomicOr(&bad, 1);
  __syncthreads();
  if (threadIdx.x == 0) *flag = bad ? 0 : 1;
}

// bucket histogram (521 bins) via LDS, one global atomic per bin per block.
__global__ __launch_bounds__(256) void k_bhist(const void* ei, const int* __restrict__ flag,
                                               int* gbh) {
  __shared__ int lh[NSB];
  int t = threadIdx.x;
  for (int i = t; i < NSB; i += 256) lh[i] = 0;
  __syncthreads();
  int base = blockIdx.x * CT;
  int is64 = *flag;
#pragma unroll
  for (int k = 0; k < 16; ++k) {
    int e = base + k * 256 + t;
    if (e < NE) {
      int d;
      if (is64) d = (int)((const long long*)ei)[NE + e];
      else      d = ((const int*)ei)[NE + e];
      atomicAdd(&lh[d / SBK], 1);
    }
  }
  __syncthreads();
  for (int i = t; i < NSB; i += 256) { int c = lh[i]; if (c) atomicAdd(&gbh[i], c); }
}

// exclusive scan of 521 bucket edge-counts (single 1024-thread block).
__global__ __launch_bounds__(1024) void k_bscan(const int* __restrict__ gbh,
                                                int* bbase, int* bcur) {
  __shared__ int sh[1024];
  int t = threadIdx.x;
  int v = (t < NSB) ? gbh[t] : 0;
  sh[t] = v;
  __syncthreads();
  int a = v;
  for (int d = 1; d < 1024; d <<= 1) {
    int add = (t >= d) ? sh[t - d] : 0;
    __syncthreads();
    a += add; sh[t] = a;
    __syncthreads();
  }
  int excl = a - v;
  if (t < NSB) { bbase[t] = excl; bcur[t] = excl; }
  if (t == NSB - 1) bbase[NSB] = excl + v;   // = NE
}

// coarse scatter: bin edges by dst-bucket; LDS ranking makes each block's
// same-bucket writes contiguous -> bucket frontier stays in L2.
__global__ __launch_bounds__(256) void k_coarse(const void* ei, const int* __restrict__ flag,
                                                const float* __restrict__ w,
                                                int* bcur, uint2* __restrict__ coarse) {
  __shared__ int lh[NSB];
  __shared__ int lbase[NSB];
  int t = threadIdx.x;
  for (int i = t; i < NSB; i += 256) lh[i] = 0;
  __syncthreads();
  int base = blockIdx.x * CT;
  int is64 = *flag;
  u32 key[16]; int wb[16], bk[16], lr[16];
#pragma unroll
  for (int k = 0; k < 16; ++k) {
    int e = base + k * 256 + t;
    if (e < NE) {
      int s, d;
      if (is64) { const long long* p = (const long long*)ei; s = (int)p[e]; d = (int)p[NE + e]; }
      else      { const int*       p = (const int*)ei;       s = p[e];      d = p[NE + e]; }
      int bb = d / SBK, dlo = d - bb * SBK;
      key[k] = (u32)s | ((u32)dlo << 17);     // src:17 bits | dlo:8 bits
      wb[k]  = __float_as_int(w[e]);
      bk[k]  = bb;
      lr[k]  = atomicAdd(&lh[bb], 1);
    }
  }
  __syncthreads();
  for (int i = t; i < NSB; i += 256) { int c = lh[i]; if (c) lbase[i] = atomicAdd(&bcur[i], c); }
  __syncthreads();
#pragma unroll
  for (int k = 0; k < 16; ++k) {
    int e = base + k * 256 + t;
    if (e < NE) coarse[lbase[bk[k]] + lr[k]] = make_uint2(key[k], (u32)wb[k]);
  }
}

// weighted degree per node from bucket-grouped coarse -> dinv.
__global__ __launch_bounds__(256) void k_dinvb(const uint2* __restrict__ coarse,
                                               const int* __restrict__ bbase,
                                               float* __restrict__ dinv) {
  __shared__ float wsum[SBK];
  int t = threadIdx.x, blk = blockIdx.x;
  for (int i = t; i < SBK; i += 256) wsum[i] = 0.f;
  __syncthreads();
  int s = bbase[blk], e = bbase[blk + 1];
  for (int j = s + t; j < e; j += 256) {
    uint2 u = coarse[j];
    atomicAdd(&wsum[u.x >> 17], __uint_as_float(u.y));
  }
  __syncthreads();
  for (int i = t; i < SBK; i += 256) {
    int node = blk * SBK + i;
    if (node < NN) dinv[node] = rsqrtf(1.0f + wsum[i]);   // +1 = self-loop
  }
}

// sup = bf16( dinv[:,None] * (x @ W) ) ; W (32KB) staged in LDS.
__global__ __launch_bounds__(256) void k_gemm(const float* __restrict__ x,
                                              const float* __restrict__ W,
                                              const float* __restrict__ dinv,
                                              u16* __restrict__ supb) {
  __shared__ float4 Wl[NF * NH / 4];
  const float4* Wg = (const float4*)W;
  for (int i = threadIdx.x; i < NF * NH / 4; i += 256) Wl[i] = Wg[i];
  __syncthreads();
  int lane16 = threadIdx.x & 15;
  int rowin  = threadIdx.x >> 4;
  const float4* x4 = (const float4*)x;
  int rowbase = blockIdx.x * 128;
  for (int r0 = 0; r0 < 128; r0 += 16) {
    int r = rowbase + r0 + rowin;
    if (r >= NN) return;
    float4 acc = make_float4(0.f, 0.f, 0.f, 0.f);
#pragma unroll 8
    for (int kk = 0; kk < NF / 4; ++kk) {
      float4 xv = x4[r * (NF / 4) + kk];
      float4 w0 = Wl[(4 * kk + 0) * 16 + lane16];
      float4 w1 = Wl[(4 * kk + 1) * 16 + lane16];
      float4 w2 = Wl[(4 * kk + 2) * 16 + lane16];
      float4 w3 = Wl[(4 * kk + 3) * 16 + lane16];
      acc.x += xv.x * w0.x + xv.y * w1.x + xv.z * w2.x + xv.w * w3.x;
      acc.y += xv.x * w0.y + xv.y * w1.y + xv.z * w2.y + xv.w * w3.y;
      acc.z += xv.x * w0.z + xv.y * w1.z + xv.z * w2.z + xv.w * w3.z;
      acc.w += xv.x * w0.w + xv.y * w1.w + xv.z * w2.w + xv.w * w3.w;
    }
    float di = dinv[r];
    ushort4 o;
    o.x = f2bf(acc.x * di); o.y = f2bf(acc.y * di);
    o.z = f2bf(acc.z * di); o.w = f2bf(acc.w * di);
    *(ushort4*)&supb[(size_t)r * NH + lane16 * 4] = o;
  }
}

// Bucket-resident aggregation + head. One block (512 thr) per 192-node bucket:
// acc[192][65] f32 in LDS (stride 65 => row AND column access conflict-free).
// __launch_bounds__(512,4): 16 waves/CU -> VGPR cap 128, no spill (round-8
// lesson: (1024,8) forced 32 VGPRs -> scratch thrash, 780us).
__global__ __launch_bounds__(512, 4) void k_agg(const uint2* __restrict__ coarse,
                                                const int* __restrict__ bbase,
                                                const float* __restrict__ dinv,
                                                const u16* __restrict__ supb,
                                                const float* __restrict__ b,
                                                const float* __restrict__ mu,
                                                float* __restrict__ z,
                                                float* __restrict__ q) {
  __shared__ float acc[SBK][65];
  __shared__ float muT[64][20];
  __shared__ float bL[64];
  int t = threadIdx.x, blk = blockIdx.x;
  int lane = t & 63, wv = t >> 6;
  int nbase = blk * SBK;

  for (int i = t; i < NK * NH; i += 512) muT[i & 63][i >> 6] = mu[i];  // mu[k][f]->muT[f][k]
  if (t < 64) bL[t] = b[t];
  for (int i = wv; i < SBK; i += AGW) {
    int node = nbase + i;
    acc[i][lane] = (node < NN) ? bf2f(supb[(size_t)node * NH + lane]) : 0.f;
  }
  __syncthreads();

  int s = bbase[blk], e = bbase[blk + 1];
  int j0 = s + wv * 8;
  for (; j0 + 8 <= e; j0 += AGW * 8) {
    uint2 u0 = coarse[j0 + 0], u1 = coarse[j0 + 1], u2 = coarse[j0 + 2], u3 = coarse[j0 + 3];
    uint2 u4 = coarse[j0 + 4], u5 = coarse[j0 + 5], u6 = coarse[j0 + 6], u7 = coarse[j0 + 7];
    float v0 = bf2f(supb[(size_t)(u0.x & 0x1FFFFu) * NH + lane]);
    float v1 = bf2f(supb[(size_t)(u1.x & 0x1FFFFu) * NH + lane]);
    float v2 = bf2f(supb[(size_t)(u2.x & 0x1FFFFu) * NH + lane]);
    float v3 = bf2f(supb[(size_t)(u3.x & 0x1FFFFu) * NH + lane]);
    float v4 = bf2f(supb[(size_t)(u4.x & 0x1FFFFu) * NH + lane]);
    float v5 = bf2f(supb[(size_t)(u5.x & 0x1FFFFu) * NH + lane]);
    float v6 = bf2f(supb[(size_t)(u6.x & 0x1FFFFu) * NH + lane]);
    float v7 = bf2f(supb[(size_t)(u7.x & 0x1FFFFu) * NH + lane]);
    atomicAdd(&acc[u0.x >> 17][lane], __uint_as_float(u0.y) * v0);
    atomicAdd(&acc[u1.x >> 17][lane], __uint_as_float(u1.y) * v1);
    atomicAdd(&acc[u2.x >> 17][lane], __uint_as_float(u2.y) * v2);
    atomicAdd(&acc[u3.x >> 17][lane], __uint_as_float(u3.y) * v3);
    atomicAdd(&acc[u4.x >> 17][lane], __uint_as_float(u4.y) * v4);
    atomicAdd(&acc[u5.x >> 17][lane], __uint_as_float(u5.y) * v5);
    atomicAdd(&acc[u6.x >> 17][lane], __uint_as_float(u6.y) * v6);
    atomicAdd(&acc[u7.x >> 17][lane], __uint_as_float(u7.y) * v7);
  }
  if (j0 < e) {
    for (int j = j0; j < e; ++j) {
      uint2 u = coarse[j];
      float v = bf2f(supb[(size_t)(u.x & 0x1FFFFu) * NH + lane]);
      atomicAdd(&acc[u.x >> 17][lane], __uint_as_float(u.y) * v);
    }
  }
  __syncthreads();

  if (wv < SBK / 64) {                      // 3 epilogue waves, lane = node
    int row  = wv * 64 + lane;
    int node = nbase + row;
    float di = (node < NN) ? dinv[node] : 0.f;
    float d2[NK];
#pragma unroll
    for (int k = 0; k < NK; ++k) d2[k] = 0.f;
    for (int f = 0; f < 64; ++f) {
      float zf = di * acc[row][f] + bL[f];  // lane stride 65 -> conflict-free
      acc[row][f] = zf;                     // stash for coalesced z store
#pragma unroll
      for (int k = 0; k < NK; ++k) {
        float dd = zf - muT[f][k];          // broadcast LDS reads
        d2[k] += dd * dd;
      }
    }
    // coalesced z store (same-wave DS ops are in order; no barrier needed)
    int grp = nbase + wv * 64;
    for (int n2 = 0; n2 < 64; ++n2) {
      int node2 = grp + n2;
      if (node2 < NN) z[(size_t)node2 * NH + lane] = acc[wv * 64 + n2][lane];
    }
    // q: everything per-lane, zero cross-lane ops
    float ssum = 0.f;
#pragma unroll
    for (int k = 0; k < NK; ++k) {
      float tq = 1.0f / (1.0f + d2[k] * (1.0f / ALPHA) + 1e-8f);
      float qe = exp2f((ALPHA + 1.0f) * __log2f(tq));
      d2[k] = qe; ssum += qe;
    }
    float rs = 1.0f / ssum;
    if (node < NN) {
#pragma unroll
      for (int k = 0; k < NK; ++k) q[(size_t)node * NK + k] = d2[k] * rs;
    }
  }
}

extern "C" void kernel_launch(void* const* d_in, const int* in_sizes, int n_in,
                              void* d_out, int out_size, void* d_ws, size_t ws_size,
                              hipStream_t stream) {
  const float* x  = (const float*)d_in[0];
  const void*  ei = d_in[1];
  const float* w  = (const float*)d_in[2];
  const float* W  = (const float*)d_in[3];
  const float* b  = (const float*)d_in[4];
  const float* mu = (const float*)d_in[5];

  char* ws = (char*)d_ws;
  int*   flag   = (int*)(ws + O_FLAG);
  float* dinv   = (float*)(ws + O_DINV);
  int*   gbh    = (int*)(ws + O_GBH);
  int*   bbase  = (int*)(ws + O_BBASE);
  int*   bcur   = (int*)(ws + O_BCUR);
  uint2* coarse = (uint2*)(ws + O_COARSE);
  u16*   supb   = (u16*)(ws + O_SUP);

  float* z = (float*)d_out;
  float* q = (float*)d_out + (size_t)NN * NH;

  hipLaunchKernelGGL(k_detect, dim3(1),                  dim3(256),  0, stream, ei, flag, gbh);
  hipLaunchKernelGGL(k_bhist,  dim3((NE + CT - 1) / CT), dim3(256),  0, stream, ei, flag, gbh);
  hipLaunchKernelGGL(k_bscan,  dim3(1),                  dim3(1024), 0, stream, gbh, bbase, bcur);
  hipLaunchKernelGGL(k_coarse, dim3((NE + CT - 1) / CT), dim3(256),  0, stream, ei, flag, w, bcur, coarse);
  hipLaunchKernelGGL(k_dinvb,  dim3(NSB),                dim3(256),  0, stream, coarse, bbase, dinv);
  hipLaunchKernelGGL(k_gemm,   dim3((NN + 127) / 128),   dim3(256),  0, stream, x, W, dinv, supb);
  hipLaunchKernelGGL(k_agg,    dim3(NSB),                dim3(512),  0, stream, coarse, bbase, dinv, supb, b, mu, z, q);
}

// Round 10
// 872.910 us; speedup vs baseline: 1.0013x; 1.0013x over previous
//
#include <hip/hip_runtime.h>

#define NN 100000
#define NE 1600000
#define NF 128
#define NH 64
#define NK 20
#define SBK 192                     // nodes per bucket (LDS acc tile)
#define NSB ((NN + SBK - 1) / SBK)  // 521 buckets
#define CT 4096                     // edges per coarse-scatter block
#define AGW 8                       // waves in k_agg block (512 threads)

static constexpr float ALPHA = 0.2f;

typedef unsigned short u16;
typedef unsigned int u32;

// ---- workspace layout (aligned to 256B) ----
constexpr size_t alup(size_t x) { return (x + 255) & ~size_t(255); }
constexpr size_t O_FLAG   = 0;                                    // 4 B
constexpr size_t O_DINV   = 256;                                  // NN f32
constexpr size_t O_GBH    = alup(O_DINV + size_t(NN) * 4);        // NSB i32 (bucket edge counts)
constexpr size_t O_BBASE  = alup(O_GBH  + size_t(NSB) * 4);       // NSB+1 i32
constexpr size_t O_BCUR   = alup(O_BBASE + size_t(NSB + 1) * 4);  // NSB i32
constexpr size_t O_COARSE = alup(O_BCUR + size_t(NSB) * 4);       // NE uint2 (12.8 MB) bucket-grouped
constexpr size_t O_SUP    = alup(O_COARSE + size_t(NE) * 8);      // NN*NH bf16 (12.8 MB), dinv-scaled x@W
// total ~ 26 MB

__device__ __forceinline__ u16 f2bf(float f) {   // RNE float->bf16
  u32 u = __float_as_uint(f);
  u32 r = (u + 0x7fffu + ((u >> 16) & 1u)) >> 16;
  return (u16)r;
}
__device__ __forceinline__ float bf2f(u16 h) {
  return __uint_as_float(((u32)h) << 16);
}

// Native no-return LDS float add. HIP's atomicAdd on __shared__ float lowers
// to a CAS loop (round-9 lesson: ~300 cyc/edge, DS-latency bound). ds_add_f32
// is fire-and-forget. LDS byte offset = low 32 bits of the generic pointer.
__device__ __forceinline__ void lds_fadd(float* p, float v) {
  u32 off = (u32)(uintptr_t)p;
  asm volatile("ds_add_f32 %0, %1" :: "v"(off), "v"(v) : "memory");
}

// edge_index dtype probe + zero the bucket histogram.
__global__ __launch_bounds__(256) void k_detect(const void* ei, int* flag, int* gbh) {
  __shared__ int bad;
  if (threadIdx.x == 0) bad = 0;
  for (int i = threadIdx.x; i < NSB; i += 256) gbh[i] = 0;
  __syncthreads();
  const long long* p = (const long long*)ei;
  int ok = 1;
#pragma unroll
  for (int k = 0; k < 4; ++k) {
    long long v = p[threadIdx.x * 4 + k];
    if (v < 0 || v >= NN) ok = 0;
  }
  if (!ok) atomicOr(&bad, 1);
  __syncthreads();
  if (threadIdx.x == 0) *flag = bad ? 0 : 1;
}

// bucket histogram (521 bins) via LDS, one global atomic per bin per block.
__global__ __launch_bounds__(256) void k_bhist(const void* ei, const int* __restrict__ flag,
                                               int* gbh) {
  __shared__ int lh[NSB];
  int t = threadIdx.x;
  for (int i = t; i < NSB; i += 256) lh[i] = 0;
  __syncthreads();
  int base = blockIdx.x * CT;
  int is64 = *flag;
#pragma unroll
  for (int k = 0; k < 16; ++k) {
    int e = base + k * 256 + t;
    if (e < NE) {
      int d;
      if (is64) d = (int)((const long long*)ei)[NE + e];
      else      d = ((const int*)ei)[NE + e];
      atomicAdd(&lh[d / SBK], 1);
    }
  }
  __syncthreads();
  for (int i = t; i < NSB; i += 256) { int c = lh[i]; if (c) atomicAdd(&gbh[i], c); }
}

// exclusive scan of 521 bucket edge-counts (single 1024-thread block).
__global__ __launch_bounds__(1024) void k_bscan(const int* __restrict__ gbh,
                                                int* bbase, int* bcur) {
  __shared__ int sh[1024];
  int t = threadIdx.x;
  int v = (t < NSB) ? gbh[t] : 0;
  sh[t] = v;
  __syncthreads();
  int a = v;
  for (int d = 1; d < 1024; d <<= 1) {
    int add = (t >= d) ? sh[t - d] : 0;
    __syncthreads();
    a += add; sh[t] = a;
    __syncthreads();
  }
  int excl = a - v;
  if (t < NSB) { bbase[t] = excl; bcur[t] = excl; }
  if (t == NSB - 1) bbase[NSB] = excl + v;   // = NE
}

// coarse scatter: bin edges by dst-bucket; LDS ranking makes each block's
// same-bucket writes contiguous -> bucket frontier stays in L2.
__global__ __launch_bounds__(256) void k_coarse(const void* ei, const int* __restrict__ flag,
                                                const float* __restrict__ w,
                                                int* bcur, uint2* __restrict__ coarse) {
  __shared__ int lh[NSB];
  __shared__ int lbase[NSB];
  int t = threadIdx.x;
  for (int i = t; i < NSB; i += 256) lh[i] = 0;
  __syncthreads();
  int base = blockIdx.x * CT;
  int is64 = *flag;
  u32 key[16]; int wb[16], bk[16], lr[16];
#pragma unroll
  for (int k = 0; k < 16; ++k) {
    int e = base + k * 256 + t;
    if (e < NE) {
      int s, d;
      if (is64) { const long long* p = (const long long*)ei; s = (int)p[e]; d = (int)p[NE + e]; }
      else      { const int*       p = (const int*)ei;       s = p[e];      d = p[NE + e]; }
      int bb = d / SBK, dlo = d - bb * SBK;
      key[k] = (u32)s | ((u32)dlo << 17);     // src:17 bits | dlo:8 bits
      wb[k]  = __float_as_int(w[e]);
      bk[k]  = bb;
      lr[k]  = atomicAdd(&lh[bb], 1);
    }
  }
  __syncthreads();
  for (int i = t; i < NSB; i += 256) { int c = lh[i]; if (c) lbase[i] = atomicAdd(&bcur[i], c); }
  __syncthreads();
#pragma unroll
  for (int k = 0; k < 16; ++k) {
    int e = base + k * 256 + t;
    if (e < NE) coarse[lbase[bk[k]] + lr[k]] = make_uint2(key[k], (u32)wb[k]);
  }
}

// weighted degree per node from bucket-grouped coarse -> dinv.
__global__ __launch_bounds__(256) void k_dinvb(const uint2* __restrict__ coarse,
                                               const int* __restrict__ bbase,
                                               float* __restrict__ dinv) {
  __shared__ float wsum[SBK];
  int t = threadIdx.x, blk = blockIdx.x;
  for (int i = t; i < SBK; i += 256) wsum[i] = 0.f;
  __syncthreads();
  int s = bbase[blk], e = bbase[blk + 1];
  for (int j = s + t; j < e; j += 256) {
    uint2 u = coarse[j];
    lds_fadd(&wsum[u.x >> 17], __uint_as_float(u.y));
  }
  asm volatile("s_waitcnt lgkmcnt(0)" ::: "memory");
  __syncthreads();
  for (int i = t; i < SBK; i += 256) {
    int node = blk * SBK + i;
    if (node < NN) dinv[node] = rsqrtf(1.0f + wsum[i]);   // +1 = self-loop
  }
}

// sup = bf16( dinv[:,None] * (x @ W) ) ; W (32KB) staged in LDS.
__global__ __launch_bounds__(256) void k_gemm(const float* __restrict__ x,
                                              const float* __restrict__ W,
                                              const float* __restrict__ dinv,
                                              u16* __restrict__ supb) {
  __shared__ float4 Wl[NF * NH / 4];
  const float4* Wg = (const float4*)W;
  for (int i = threadIdx.x; i < NF * NH / 4; i += 256) Wl[i] = Wg[i];
  __syncthreads();
  int lane16 = threadIdx.x & 15;
  int rowin  = threadIdx.x >> 4;
  const float4* x4 = (const float4*)x;
  int rowbase = blockIdx.x * 128;
  for (int r0 = 0; r0 < 128; r0 += 16) {
    int r = rowbase + r0 + rowin;
    if (r >= NN) return;
    float4 acc = make_float4(0.f, 0.f, 0.f, 0.f);
#pragma unroll 8
    for (int kk = 0; kk < NF / 4; ++kk) {
      float4 xv = x4[r * (NF / 4) + kk];
      float4 w0 = Wl[(4 * kk + 0) * 16 + lane16];
      float4 w1 = Wl[(4 * kk + 1) * 16 + lane16];
      float4 w2 = Wl[(4 * kk + 2) * 16 + lane16];
      float4 w3 = Wl[(4 * kk + 3) * 16 + lane16];
      acc.x += xv.x * w0.x + xv.y * w1.x + xv.z * w2.x + xv.w * w3.x;
      acc.y += xv.x * w0.y + xv.y * w1.y + xv.z * w2.y + xv.w * w3.y;
      acc.z += xv.x * w0.z + xv.y * w1.z + xv.z * w2.z + xv.w * w3.z;
      acc.w += xv.x * w0.w + xv.y * w1.w + xv.z * w2.w + xv.w * w3.w;
    }
    float di = dinv[r];
    ushort4 o;
    o.x = f2bf(acc.x * di); o.y = f2bf(acc.y * di);
    o.z = f2bf(acc.z * di); o.w = f2bf(acc.w * di);
    *(ushort4*)&supb[(size_t)r * NH + lane16 * 4] = o;
  }
}

// Bucket-resident aggregation + head. One block (512 thr) per 192-node bucket:
// acc[192][65] f32 in LDS (stride 65 => row AND column access conflict-free).
// Edge loop uses native ds_add_f32 (no CAS loop, fire-and-forget).
__global__ __launch_bounds__(512, 4) void k_agg(const uint2* __restrict__ coarse,
                                                const int* __restrict__ bbase,
                                                const float* __restrict__ dinv,
                                                const u16* __restrict__ supb,
                                                const float* __restrict__ b,
                                                const float* __restrict__ mu,
                                                float* __restrict__ z,
                                                float* __restrict__ q) {
  __shared__ float acc[SBK][65];
  __shared__ float muT[64][20];
  __shared__ float bL[64];
  int t = threadIdx.x, blk = blockIdx.x;
  int lane = t & 63, wv = t >> 6;
  int nbase = blk * SBK;

  for (int i = t; i < NK * NH; i += 512) muT[i & 63][i >> 6] = mu[i];  // mu[k][f]->muT[f][k]
  if (t < 64) bL[t] = b[t];
  for (int i = wv; i < SBK; i += AGW) {
    int node = nbase + i;
    acc[i][lane] = (node < NN) ? bf2f(supb[(size_t)node * NH + lane]) : 0.f;
  }
  __syncthreads();

  int s = bbase[blk], e = bbase[blk + 1];
  int j0 = s + wv * 8;
  for (; j0 + 8 <= e; j0 += AGW * 8) {
    uint2 u0 = coarse[j0 + 0], u1 = coarse[j0 + 1], u2 = coarse[j0 + 2], u3 = coarse[j0 + 3];
    uint2 u4 = coarse[j0 + 4], u5 = coarse[j0 + 5], u6 = coarse[j0 + 6], u7 = coarse[j0 + 7];
    float v0 = bf2f(supb[(size_t)(u0.x & 0x1FFFFu) * NH + lane]);
    float v1 = bf2f(supb[(size_t)(u1.x & 0x1FFFFu) * NH + lane]);
    float v2 = bf2f(supb[(size_t)(u2.x & 0x1FFFFu) * NH + lane]);
    float v3 = bf2f(supb[(size_t)(u3.x & 0x1FFFFu) * NH + lane]);
    float v4 = bf2f(supb[(size_t)(u4.x & 0x1FFFFu) * NH + lane]);
    float v5 = bf2f(supb[(size_t)(u5.x & 0x1FFFFu) * NH + lane]);
    float v6 = bf2f(supb[(size_t)(u6.x & 0x1FFFFu) * NH + lane]);
    float v7 = bf2f(supb[(size_t)(u7.x & 0x1FFFFu) * NH + lane]);
    lds_fadd(&acc[u0.x >> 17][lane], __uint_as_float(u0.y) * v0);
    lds_fadd(&acc[u1.x >> 17][lane], __uint_as_float(u1.y) * v1);
    lds_fadd(&acc[u2.x >> 17][lane], __uint_as_float(u2.y) * v2);
    lds_fadd(&acc[u3.x >> 17][lane], __uint_as_float(u3.y) * v3);
    lds_fadd(&acc[u4.x >> 17][lane], __uint_as_float(u4.y) * v4);
    lds_fadd(&acc[u5.x >> 17][lane], __uint_as_float(u5.y) * v5);
    lds_fadd(&acc[u6.x >> 17][lane], __uint_as_float(u6.y) * v6);
    lds_fadd(&acc[u7.x >> 17][lane], __uint_as_float(u7.y) * v7);
  }
  if (j0 < e) {
    for (int j = j0; j < e; ++j) {
      uint2 u = coarse[j];
      float v = bf2f(supb[(size_t)(u.x & 0x1FFFFu) * NH + lane]);
      lds_fadd(&acc[u.x >> 17][lane], __uint_as_float(u.y) * v);
    }
  }
  // drain inline-asm DS ops (compiler's waitcnt tracker doesn't see them)
  asm volatile("s_waitcnt lgkmcnt(0)" ::: "memory");
  __syncthreads();

  if (wv < SBK / 64) {                      // 3 epilogue waves, lane = node
    int row  = wv * 64 + lane;
    int node = nbase + row;
    float di = (node < NN) ? dinv[node] : 0.f;
    float d2[NK];
#pragma unroll
    for (int k = 0; k < NK; ++k) d2[k] = 0.f;
    for (int f = 0; f < 64; ++f) {
      float zf = di * acc[row][f] + bL[f];  // lane stride 65 -> conflict-free
      acc[row][f] = zf;                     // stash for coalesced z store
#pragma unroll
      for (int k = 0; k < NK; ++k) {
        float dd = zf - muT[f][k];          // broadcast LDS reads
        d2[k] += dd * dd;
      }
    }
    // coalesced z store (same-wave DS ops are in order; no barrier needed)
    int grp = nbase + wv * 64;
    for (int n2 = 0; n2 < 64; ++n2) {
      int node2 = grp + n2;
      if (node2 < NN) z[(size_t)node2 * NH + lane] = acc[wv * 64 + n2][lane];
    }
    // q: everything per-lane, zero cross-lane ops
    float ssum = 0.f;
#pragma unroll
    for (int k = 0; k < NK; ++k) {
      float tq = 1.0f / (1.0f + d2[k] * (1.0f / ALPHA) + 1e-8f);
      float qe = exp2f((ALPHA + 1.0f) * __log2f(tq));
      d2[k] = qe; ssum += qe;
    }
    float rs = 1.0f / ssum;
    if (node < NN) {
#pragma unroll
      for (int k = 0; k < NK; ++k) q[(size_t)node * NK + k] = d2[k] * rs;
    }
  }
}

extern "C" void kernel_launch(void* const* d_in, const int* in_sizes, int n_in,
                              void* d_out, int out_size, void* d_ws, size_t ws_size,
                              hipStream_t stream) {
  const float* x  = (const float*)d_in[0];
  const void*  ei = d_in[1];
  const float* w  = (const float*)d_in[2];
  const float* W  = (const float*)d_in[3];
  const float* b  = (const float*)d_in[4];
  const float* mu = (const float*)d_in[5];

  char* ws = (char*)d_ws;
  int*   flag   = (int*)(ws + O_FLAG);
  float* dinv   = (float*)(ws + O_DINV);
  int*   gbh    = (int*)(ws + O_GBH);
  int*   bbase  = (int*)(ws + O_BBASE);
  int*   bcur   = (int*)(ws + O_BCUR);
  uint2* coarse = (uint2*)(ws + O_COARSE);
  u16*   supb   = (u16*)(ws + O_SUP);

  float* z = (float*)d_out;
  float* q = (float*)d_out + (size_t)NN * NH;

  hipLaunchKernelGGL(k_detect, dim3(1),                  dim3(256),  0, stream, ei, flag, gbh);
  hipLaunchKernelGGL(k_bhist,  dim3((NE + CT - 1) / CT), dim3(256),  0, stream, ei, flag, gbh);
  hipLaunchKernelGGL(k_bscan,  dim3(1),                  dim3(1024), 0, stream, gbh, bbase, bcur);
  hipLaunchKernelGGL(k_coarse, dim3((NE + CT - 1) / CT), dim3(256),  0, stream, ei, flag, w, bcur, coarse);
  hipLaunchKernelGGL(k_dinvb,  dim3(NSB),                dim3(256),  0, stream, coarse, bbase, dinv);
  hipLaunchKernelGGL(k_gemm,   dim3((NN + 127) / 128),   dim3(256),  0, stream, x, W, dinv, supb);
  hipLaunchKernelGGL(k_agg,    dim3(NSB),                dim3(512),  0, stream, coarse, bbase, dinv, supb, b, mu, z, q);
}

// Round 11
// 191.968 us; speedup vs baseline: 4.5531x; 4.5472x over previous
//
#include <hip/hip_runtime.h>

#define NN 100000
#define NE 1600000
#define NF 128
#define NH 64
#define NK 20
#define SBK 512                     // sort-bucket: nodes per bucket
#define NSB ((NN + SBK - 1) / SBK)  // 196 buckets
#define CT 4096                     // edges per coarse-scatter block
#define PAD 8
#define MAXPAIRS (size_t(NE) + size_t(PAD) * NN)   // 2.4M pairs

static constexpr float ALPHA = 0.2f;

typedef unsigned short u16;
typedef unsigned int u32;

// ---- workspace layout (aligned to 256B) ----
constexpr size_t alup(size_t x) { return (x + 255) & ~size_t(255); }
constexpr size_t O_FLAG   = 0;                                    // 4 B
constexpr size_t O_DINV   = 256;                                  // NN f32
constexpr size_t O_HIST   = alup(O_DINV + size_t(NN) * 4);        // NN i32 (real counts)
constexpr size_t O_OFF    = alup(O_HIST + size_t(NN) * 4);        // (NN+1) i32 (padded offsets)
constexpr size_t O_GBH    = alup(O_OFF  + size_t(NN + 1) * 4);    // NSB i32
constexpr size_t O_BBASE  = alup(O_GBH  + size_t(NSB) * 4);       // NSB+1 i32
constexpr size_t O_BCUR   = alup(O_BBASE + size_t(NSB + 1) * 4);  // NSB i32
constexpr size_t O_BSUM   = alup(O_BCUR + size_t(NSB) * 4);       // NSB i32
constexpr size_t O_OBASE  = alup(O_BSUM + size_t(NSB) * 4);       // NSB+1 i32
constexpr size_t O_COARSE = alup(O_OBASE + size_t(NSB + 1) * 4);  // NE uint2 (12.8 MB)
constexpr size_t O_EPAIR  = alup(O_COARSE + size_t(NE) * 8);      // MAXPAIRS int2 (19.2 MB)
constexpr size_t O_SUP    = alup(O_EPAIR + MAXPAIRS * 8);         // NN*NH bf16 (12.8 MB)
// total ~ 46 MB

__device__ __forceinline__ u16 f2bf(float f) {   // RNE float->bf16
  u32 u = __float_as_uint(f);
  u32 r = (u + 0x7fffu + ((u >> 16) & 1u)) >> 16;
  return (u16)r;
}
__device__ __forceinline__ float bf2f(u16 h) {
  return __uint_as_float(((u32)h) << 16);
}
__device__ __forceinline__ float gath(const u16* supb, u32 byteoff) {
  return bf2f(*(const u16*)((const char*)supb + byteoff));
}

// edge_index dtype probe + zero the bucket histogram.
__global__ __launch_bounds__(256) void k_detect(const void* ei, int* flag, int* gbh) {
  __shared__ int bad;
  if (threadIdx.x == 0) bad = 0;
  if (threadIdx.x < NSB) gbh[threadIdx.x] = 0;
  __syncthreads();
  const long long* p = (const long long*)ei;
  int ok = 1;
#pragma unroll
  for (int k = 0; k < 4; ++k) {
    long long v = p[threadIdx.x * 4 + k];
    if (v < 0 || v >= NN) ok = 0;
  }
  if (!ok) atomicOr(&bad, 1);
  __syncthreads();
  if (threadIdx.x == 0) *flag = bad ? 0 : 1;
}

// bucket histogram (196 bins) via LDS.
__global__ __launch_bounds__(256) void k_bhist(const void* ei, const int* __restrict__ flag,
                                               int* gbh) {
  __shared__ int lh[NSB];
  int t = threadIdx.x;
  for (int i = t; i < NSB; i += 256) lh[i] = 0;
  __syncthreads();
  int base = blockIdx.x * CT;
  int is64 = *flag;
#pragma unroll
  for (int k = 0; k < 16; ++k) {
    int e = base + k * 256 + t;
    if (e < NE) {
      int d;
      if (is64) d = (int)((const long long*)ei)[NE + e];
      else      d = ((const int*)ei)[NE + e];
      atomicAdd(&lh[d >> 9], 1);
    }
  }
  __syncthreads();
  if (t < NSB) { int c = lh[t]; if (c) atomicAdd(&gbh[t], c); }
}

// exclusive scan of 196 bucket edge-counts.
__global__ __launch_bounds__(256) void k_bscan(const int* __restrict__ gbh,
                                               int* bbase, int* bcur) {
  __shared__ int sh[256];
  int t = threadIdx.x;
  int v = (t < NSB) ? gbh[t] : 0;
  sh[t] = v;
  __syncthreads();
  int a = v;
  for (int d = 1; d < 256; d <<= 1) {
    int add = (t >= d) ? sh[t - d] : 0;
    __syncthreads();
    a += add; sh[t] = a;
    __syncthreads();
  }
  int excl = a - v;
  if (t < NSB) { bbase[t] = excl; bcur[t] = excl; }
  if (t == NSB - 1) bbase[NSB] = excl + v;   // = NE
}

// coarse scatter: bin edges by dst-bucket; LDS ranking -> contiguous writes.
__global__ __launch_bounds__(256) void k_coarse(const void* ei, const int* __restrict__ flag,
                                                const float* __restrict__ w,
                                                int* bcur, uint2* __restrict__ coarse) {
  __shared__ int lh[NSB];
  __shared__ int lbase[NSB];
  int t = threadIdx.x;
  for (int i = t; i < NSB; i += 256) lh[i] = 0;
  __syncthreads();
  int base = blockIdx.x * CT;
  int is64 = *flag;
  u32 key[16]; int wb[16], bk[16], lr[16];
#pragma unroll
  for (int k = 0; k < 16; ++k) {
    int e = base + k * 256 + t;
    if (e < NE) {
      int s, d;
      if (is64) { const long long* p = (const long long*)ei; s = (int)p[e]; d = (int)p[NE + e]; }
      else      { const int*       p = (const int*)ei;       s = p[e];      d = p[NE + e]; }
      int bb = d >> 9, dlo = d & 511;
      key[k] = (u32)s | ((u32)dlo << 17);     // src:17 | dlo:9
      wb[k]  = __float_as_int(w[e]);
      bk[k]  = bb;
      lr[k]  = atomicAdd(&lh[bb], 1);
    }
  }
  __syncthreads();
  if (t < NSB) { int c = lh[t]; if (c) lbase[t] = atomicAdd(&bcur[t], c); }
  __syncthreads();
#pragma unroll
  for (int k = 0; k < 16; ++k) {
    int e = base + k * 256 + t;
    if (e < NE) coarse[lbase[bk[k]] + lr[k]] = make_uint2(key[k], (u32)wb[k]);
  }
}

// per-node counts + weighted degree + per-bucket padded sums.
__global__ __launch_bounds__(256) void k_nhist(const uint2* __restrict__ coarse,
                                               const int* __restrict__ bbase,
                                               int* __restrict__ hist,
                                               float* __restrict__ dinv,
                                               int* __restrict__ bsum) {
  __shared__ int cnt[SBK];
  __shared__ float wsum[SBK];
  __shared__ int wt[4];
  int t = threadIdx.x, b = blockIdx.x;
  for (int i = t; i < SBK; i += 256) { cnt[i] = 0; wsum[i] = 0.f; }
  __syncthreads();
  int s = bbase[b], e = bbase[b + 1];
  for (int j = s + t; j < e; j += 256) {
    uint2 u = coarse[j];
    int dlo = u.x >> 17;
    atomicAdd(&cnt[dlo], 1);
    atomicAdd(&wsum[dlo], __uint_as_float(u.y));
  }
  __syncthreads();
  int ps = 0;
  for (int i = t; i < SBK; i += 256) {
    int node = b * SBK + i;
    if (node < NN) {
      int c = cnt[i];
      hist[node] = c;
      dinv[node] = rsqrtf(1.0f + wsum[i]);
      ps += (c + (PAD - 1)) & ~(PAD - 1);
    }
  }
  for (int o = 32; o; o >>= 1) ps += __shfl_xor(ps, o, 64);
  if ((t & 63) == 0) wt[t >> 6] = ps;
  __syncthreads();
  if (t == 0) bsum[b] = wt[0] + wt[1] + wt[2] + wt[3];
}

// exclusive scan of padded bucket sums -> obase; writes off[NN].
__global__ __launch_bounds__(256) void k_bscan2(const int* __restrict__ bsum,
                                                int* obase, int* off) {
  __shared__ int sh[256];
  int t = threadIdx.x;
  int v = (t < NSB) ? bsum[t] : 0;
  sh[t] = v;
  __syncthreads();
  int a = v;
  for (int d = 1; d < 256; d <<= 1) {
    int add = (t >= d) ? sh[t - d] : 0;
    __syncthreads();
    a += add; sh[t] = a;
    __syncthreads();
  }
  int excl = a - v;
  if (t < NSB) obase[t] = excl;
  if (t == NSB - 1) { obase[NSB] = excl + v; off[NN] = excl + v; }
}

// fine scatter: one block per bucket; in-block scan -> off; pads filled here.
__global__ __launch_bounds__(256) void k_fine(const uint2* __restrict__ coarse,
                                              const int* __restrict__ bbase,
                                              const int* __restrict__ obase,
                                              const int* __restrict__ hist,
                                              int* __restrict__ off,
                                              int2* __restrict__ epair) {
  __shared__ int cur[SBK];
  __shared__ int endi[SBK];
  __shared__ int wtot[4];
  int t = threadIdx.x, b = blockIdx.x;
  int n0 = b * SBK + t * 2, n1 = n0 + 1;
  int c0r = (n0 < NN) ? hist[n0] : 0;
  int c1r = (n1 < NN) ? hist[n1] : 0;
  int c0 = (c0r + (PAD - 1)) & ~(PAD - 1);
  int c1 = (c1r + (PAD - 1)) & ~(PAD - 1);
  int sum2 = c0 + c1;
  int lane = t & 63, wv = t >> 6;
  int inc = sum2;
  for (int d = 1; d < 64; d <<= 1) { int tt = __shfl_up(inc, d, 64); if (lane >= d) inc += tt; }
  if (lane == 63) wtot[wv] = inc;
  __syncthreads();
  int wbase = 0;
#pragma unroll
  for (int k = 0; k < 4; ++k) if (k < wv) wbase += wtot[k];
  int base0 = obase[b] + wbase + (inc - sum2);
  int base1 = base0 + c0;
  if (n0 < NN) off[n0] = base0;
  if (n1 < NN) off[n1] = base1;
  cur[t * 2]     = base0;
  cur[t * 2 + 1] = base1;
  endi[t * 2]     = base0 + c0;
  endi[t * 2 + 1] = base1 + c1;
  __syncthreads();
  int s = bbase[b], e = bbase[b + 1];
  for (int j = s + t; j < e; j += 256) {
    uint2 u = coarse[j];
    int dlo = u.x >> 17;
    int src = u.x & 0x1FFFF;
    int pos = atomicAdd(&cur[dlo], 1);
    epair[pos] = make_int2(src, (int)u.y);
  }
  __syncthreads();
#pragma unroll
  for (int h = 0; h < 2; ++h) {
    int i = t * 2 + h;
    for (int p = cur[i]; p < endi[i]; ++p) epair[p] = make_int2(0, 0);
  }
}

// sup = bf16( dinv[:,None] * (x @ W) ) ; W (32KB) staged in LDS.
__global__ __launch_bounds__(256) void k_gemm(const float* __restrict__ x,
                                              const float* __restrict__ W,
                                              const float* __restrict__ dinv,
                                              u16* __restrict__ supb) {
  __shared__ float4 Wl[NF * NH / 4];
  const float4* Wg = (const float4*)W;
  for (int i = threadIdx.x; i < NF * NH / 4; i += 256) Wl[i] = Wg[i];
  __syncthreads();
  int lane16 = threadIdx.x & 15;
  int rowin  = threadIdx.x >> 4;
  const float4* x4 = (const float4*)x;
  int rowbase = blockIdx.x * 128;
  for (int r0 = 0; r0 < 128; r0 += 16) {
    int r = rowbase + r0 + rowin;
    if (r >= NN) return;
    float4 acc = make_float4(0.f, 0.f, 0.f, 0.f);
#pragma unroll 8
    for (int kk = 0; kk < NF / 4; ++kk) {
      float4 xv = x4[r * (NF / 4) + kk];
      float4 w0 = Wl[(4 * kk + 0) * 16 + lane16];
      float4 w1 = Wl[(4 * kk + 1) * 16 + lane16];
      float4 w2 = Wl[(4 * kk + 2) * 16 + lane16];
      float4 w3 = Wl[(4 * kk + 3) * 16 + lane16];
      acc.x += xv.x * w0.x + xv.y * w1.x + xv.z * w2.x + xv.w * w3.x;
      acc.y += xv.x * w0.y + xv.y * w1.y + xv.z * w2.y + xv.w * w3.y;
      acc.z += xv.x * w0.z + xv.y * w1.z + xv.z * w2.z + xv.w * w3.z;
      acc.w += xv.x * w0.w + xv.y * w1.w + xv.z * w2.w + xv.w * w3.w;
    }
    float di = dinv[r];
    ushort4 o;
    o.x = f2bf(acc.x * di); o.y = f2bf(acc.y * di);
    o.z = f2bf(acc.z * di); o.w = f2bf(acc.w * di);
    *(ushort4*)&supb[(size_t)r * NH + lane16 * 4] = o;
  }
}

// One wave per node: padded segment-reduce (8 gathers in flight, u32 saddr
// offsets, int4 edge loads), then LDS-transpose Student-t head (round-6 form).
__global__ __launch_bounds__(256) void k_agg_q(const int2* __restrict__ epair,
                                               const int* __restrict__ off,
                                               const float* __restrict__ dinv,
                                               const u16* __restrict__ supb,
                                               const float* __restrict__ b,
                                               const float* __restrict__ mu,
                                               float* __restrict__ z,
                                               float* __restrict__ q) {
  __shared__ float muL[NK * 68];    // padded rows break bank aliasing
  __shared__ float zsh[4][64];
  for (int i = threadIdx.x; i < NK * NH; i += 256) muL[(i >> 6) * 68 + (i & 63)] = mu[i];
  __syncthreads();
  int wid  = (blockIdx.x * 256 + threadIdx.x) >> 6;  // node
  int lane = threadIdx.x & 63;                       // feature
  int wv   = threadIdx.x >> 6;

  int startU = __builtin_amdgcn_readfirstlane(off[wid]);
  int endU   = __builtin_amdgcn_readfirstlane(off[wid + 1]);
  float di  = dinv[wid];
  u32 loff = (u32)lane << 1;
  float acc0 = gath(supb, ((u32)wid << 7) + loff);   // self-loop term
  float acc1 = 0.f;

  for (int j = startU; j < endU; j += 8) {
    int4 p01 = *(const int4*)&epair[j + 0];
    int4 p23 = *(const int4*)&epair[j + 2];
    int4 p45 = *(const int4*)&epair[j + 4];
    int4 p67 = *(const int4*)&epair[j + 6];
    float v0 = gath(supb, ((u32)p01.x << 7) + loff);
    float v1 = gath(supb, ((u32)p01.z << 7) + loff);
    float v2 = gath(supb, ((u32)p23.x << 7) + loff);
    float v3 = gath(supb, ((u32)p23.z << 7) + loff);
    float v4 = gath(supb, ((u32)p45.x << 7) + loff);
    float v5 = gath(supb, ((u32)p45.z << 7) + loff);
    float v6 = gath(supb, ((u32)p67.x << 7) + loff);
    float v7 = gath(supb, ((u32)p67.z << 7) + loff);
    acc0 += __int_as_float(p01.y) * v0;
    acc1 += __int_as_float(p01.w) * v1;
    acc0 += __int_as_float(p23.y) * v2;
    acc1 += __int_as_float(p23.w) * v3;
    acc0 += __int_as_float(p45.y) * v4;
    acc1 += __int_as_float(p45.w) * v5;
    acc0 += __int_as_float(p67.y) * v6;
    acc1 += __int_as_float(p67.w) * v7;
  }

  float zz = di * (acc0 + acc1) + b[lane];
  z[(size_t)wid * NH + lane] = zz;
  zsh[wv][lane] = zz;   // same-wave write->read

  float qv = 0.f;
  if (lane < NK) {
    const float4* zr = (const float4*)zsh[wv];          // broadcast reads
    const float4* mr = (const float4*)&muL[lane * 68];  // per-lane mu row
    float s0 = 0.f, s1 = 0.f, s2 = 0.f, s3 = 0.f;
#pragma unroll
    for (int j = 0; j < 16; ++j) {
      float4 zv = zr[j];
      float4 mv = mr[j];
      float a0 = zv.x - mv.x, a1 = zv.y - mv.y, a2 = zv.z - mv.z, a3 = zv.w - mv.w;
      s0 += a0 * a0; s1 += a1 * a1; s2 += a2 * a2; s3 += a3 * a3;
    }
    float d2 = (s0 + s1) + (s2 + s3);
    float tq = 1.0f / (1.0f + d2 * (1.0f / ALPHA) + 1e-8f);
    qv = exp2f((ALPHA + 1.0f) * __log2f(tq));   // /2 cancels in normalization
  }
  float ssum = qv;
  for (int o = 32; o; o >>= 1) ssum += __shfl_xor(ssum, o, 64);
  if (lane < NK) q[(size_t)wid * NK + lane] = qv / ssum;
}

extern "C" void kernel_launch(void* const* d_in, const int* in_sizes, int n_in,
                              void* d_out, int out_size, void* d_ws, size_t ws_size,
                              hipStream_t stream) {
  const float* x  = (const float*)d_in[0];
  const void*  ei = d_in[1];
  const float* w  = (const float*)d_in[2];
  const float* W  = (const float*)d_in[3];
  const float* b  = (const float*)d_in[4];
  const float* mu = (const float*)d_in[5];

  char* ws = (char*)d_ws;
  int*   flag   = (int*)(ws + O_FLAG);
  float* dinv   = (float*)(ws + O_DINV);
  int*   hist   = (int*)(ws + O_HIST);
  int*   off    = (int*)(ws + O_OFF);
  int*   gbh    = (int*)(ws + O_GBH);
  int*   bbase  = (int*)(ws + O_BBASE);
  int*   bcur   = (int*)(ws + O_BCUR);
  int*   bsum   = (int*)(ws + O_BSUM);
  int*   obase  = (int*)(ws + O_OBASE);
  uint2* coarse = (uint2*)(ws + O_COARSE);
  int2*  epair  = (int2*)(ws + O_EPAIR);
  u16*   supb   = (u16*)(ws + O_SUP);

  float* z = (float*)d_out;
  float* q = (float*)d_out + (size_t)NN * NH;

  hipLaunchKernelGGL(k_detect, dim3(1),                   dim3(256), 0, stream, ei, flag, gbh);
  hipLaunchKernelGGL(k_bhist,  dim3((NE + CT - 1) / CT),  dim3(256), 0, stream, ei, flag, gbh);
  hipLaunchKernelGGL(k_bscan,  dim3(1),                   dim3(256), 0, stream, gbh, bbase, bcur);
  hipLaunchKernelGGL(k_coarse, dim3((NE + CT - 1) / CT),  dim3(256), 0, stream, ei, flag, w, bcur, coarse);
  hipLaunchKernelGGL(k_nhist,  dim3(NSB),                 dim3(256), 0, stream, coarse, bbase, hist, dinv, bsum);
  hipLaunchKernelGGL(k_bscan2, dim3(1),                   dim3(256), 0, stream, bsum, obase, off);
  hipLaunchKernelGGL(k_fine,   dim3(NSB),                 dim3(256), 0, stream, coarse, bbase, obase, hist, off, epair);
  hipLaunchKernelGGL(k_gemm,   dim3((NN + 127) / 128),    dim3(256), 0, stream, x, W, dinv, supb);
  hipLaunchKernelGGL(k_agg_q,  dim3((NN * 64) / 256),     dim3(256), 0, stream, epair, off, dinv, supb, b, mu, z, q);
}

// Round 12
// 176.417 us; speedup vs baseline: 4.9544x; 1.0881x over previous
//
#include <hip/hip_runtime.h>

#define NN 100000
#define NE 1600000
#define NF 128
#define NH 64
#define NK 20
#define SBK 512                     // sort-bucket: nodes per bucket
#define NSB ((NN + SBK - 1) / SBK)  // 196 buckets
#define CAP 9216                    // fixed coarse capacity per bucket (mean 8163 + 11.7 sigma)
#define CT 4096                     // edges per coarse-scatter block
#define PAD 8
#define MAXPAIRS (size_t(NE) + size_t(PAD) * NN)   // 2.4M pairs

static constexpr float ALPHA = 0.2f;

typedef unsigned short u16;
typedef unsigned int u32;

// ---- workspace layout (aligned to 256B) ----
constexpr size_t alup(size_t x) { return (x + 255) & ~size_t(255); }
constexpr size_t O_FLAG   = 0;                                    // 4 B
constexpr size_t O_DINV   = 256;                                  // NN f32
constexpr size_t O_HIST   = alup(O_DINV + size_t(NN) * 4);        // NN i32 (real counts)
constexpr size_t O_OFF    = alup(O_HIST + size_t(NN) * 4);        // (NN+1) i32 (padded offsets)
constexpr size_t O_BCUR   = alup(O_OFF  + size_t(NN + 1) * 4);    // NSB i32 (coarse cursors)
constexpr size_t O_BSUM   = alup(O_BCUR + size_t(NSB) * 4);       // NSB i32 (bucket padded sums)
constexpr size_t O_OBASE  = alup(O_BSUM + size_t(NSB) * 4);       // NSB+1 i32
constexpr size_t O_COARSE = alup(O_OBASE + size_t(NSB + 1) * 4);  // NSB*CAP uint2 (14.5 MB)
constexpr size_t O_EPAIR  = alup(O_COARSE + size_t(NSB) * CAP * 8); // MAXPAIRS int2 (19.2 MB)
constexpr size_t O_SUP    = alup(O_EPAIR + MAXPAIRS * 8);         // NN*NH bf16 (12.8 MB)
// total ~ 47.5 MB

__device__ __forceinline__ u16 f2bf(float f) {   // RNE float->bf16
  u32 u = __float_as_uint(f);
  u32 r = (u + 0x7fffu + ((u >> 16) & 1u)) >> 16;
  return (u16)r;
}
__device__ __forceinline__ float bf2f(u16 h) {
  return __uint_as_float(((u32)h) << 16);
}
__device__ __forceinline__ float gath(const u16* supb, u32 byteoff) {
  return bf2f(*(const u16*)((const char*)supb + byteoff));
}

// edge_index dtype probe + init the bucket cursors to fixed-capacity bases.
__global__ __launch_bounds__(256) void k_detect(const void* ei, int* flag, int* bcur) {
  __shared__ int bad;
  if (threadIdx.x == 0) bad = 0;
  if (threadIdx.x < NSB) bcur[threadIdx.x] = threadIdx.x * CAP;
  __syncthreads();
  const long long* p = (const long long*)ei;
  int ok = 1;
#pragma unroll
  for (int k = 0; k < 4; ++k) {
    long long v = p[threadIdx.x * 4 + k];
    if (v < 0 || v >= NN) ok = 0;
  }
  if (!ok) atomicOr(&bad, 1);
  __syncthreads();
  if (threadIdx.x == 0) *flag = bad ? 0 : 1;
}

// coarse scatter: bin edges by dst-bucket into fixed-capacity regions;
// LDS ranking -> contiguous writes; bucket frontier (196 lines) stays in L2.
__global__ __launch_bounds__(256) void k_coarse(const void* ei, const int* __restrict__ flag,
                                                const float* __restrict__ w,
                                                int* bcur, uint2* __restrict__ coarse) {
  __shared__ int lh[NSB];
  __shared__ int lbase[NSB];
  int t = threadIdx.x;
  for (int i = t; i < NSB; i += 256) lh[i] = 0;
  __syncthreads();
  int base = blockIdx.x * CT;
  int is64 = *flag;
  u32 key[16]; int wb[16], bk[16], lr[16];
#pragma unroll
  for (int k = 0; k < 16; ++k) {
    int e = base + k * 256 + t;
    if (e < NE) {
      int s, d;
      if (is64) { const long long* p = (const long long*)ei; s = (int)p[e]; d = (int)p[NE + e]; }
      else      { const int*       p = (const int*)ei;       s = p[e];      d = p[NE + e]; }
      int bb = d >> 9, dlo = d & 511;
      key[k] = (u32)s | ((u32)dlo << 17);     // src:17 | dlo:9
      wb[k]  = __float_as_int(w[e]);
      bk[k]  = bb;
      lr[k]  = atomicAdd(&lh[bb], 1);
    }
  }
  __syncthreads();
  if (t < NSB) { int c = lh[t]; if (c) lbase[t] = atomicAdd(&bcur[t], c); }
  __syncthreads();
#pragma unroll
  for (int k = 0; k < 16; ++k) {
    int e = base + k * 256 + t;
    if (e < NE) coarse[lbase[bk[k]] + lr[k]] = make_uint2(key[k], (u32)wb[k]);
  }
}

// per-node counts + weighted degree + per-bucket padded sums.
__global__ __launch_bounds__(256) void k_nhist(const uint2* __restrict__ coarse,
                                               const int* __restrict__ bcur,
                                               int* __restrict__ hist,
                                               float* __restrict__ dinv,
                                               int* __restrict__ bsum) {
  __shared__ int cnt[SBK];
  __shared__ float wsum[SBK];
  __shared__ int wt[4];
  int t = threadIdx.x, b = blockIdx.x;
  for (int i = t; i < SBK; i += 256) { cnt[i] = 0; wsum[i] = 0.f; }
  __syncthreads();
  int s = b * CAP, e = bcur[b];
  for (int j = s + t; j < e; j += 256) {
    uint2 u = coarse[j];
    int dlo = u.x >> 17;
    atomicAdd(&cnt[dlo], 1);
    atomicAdd(&wsum[dlo], __uint_as_float(u.y));
  }
  __syncthreads();
  int ps = 0;
  for (int i = t; i < SBK; i += 256) {
    int node = b * SBK + i;
    if (node < NN) {
      int c = cnt[i];
      hist[node] = c;
      dinv[node] = rsqrtf(1.0f + wsum[i]);
      ps += (c + (PAD - 1)) & ~(PAD - 1);
    }
  }
  for (int o = 32; o; o >>= 1) ps += __shfl_xor(ps, o, 64);
  if ((t & 63) == 0) wt[t >> 6] = ps;
  __syncthreads();
  if (t == 0) bsum[b] = wt[0] + wt[1] + wt[2] + wt[3];
}

// exclusive scan of padded bucket sums -> obase; writes off[NN].
__global__ __launch_bounds__(256) void k_bscan2(const int* __restrict__ bsum,
                                                int* obase, int* off) {
  __shared__ int sh[256];
  int t = threadIdx.x;
  int v = (t < NSB) ? bsum[t] : 0;
  sh[t] = v;
  __syncthreads();
  int a = v;
  for (int d = 1; d < 256; d <<= 1) {
    int add = (t >= d) ? sh[t - d] : 0;
    __syncthreads();
    a += add; sh[t] = a;
    __syncthreads();
  }
  int excl = a - v;
  if (t < NSB) obase[t] = excl;
  if (t == NSB - 1) { obase[NSB] = excl + v; off[NN] = excl + v; }
}

// fine scatter: one block per bucket; in-block scan -> off; pads filled here.
__global__ __launch_bounds__(256) void k_fine(const uint2* __restrict__ coarse,
                                              const int* __restrict__ bcur,
                                              const int* __restrict__ obase,
                                              const int* __restrict__ hist,
                                              int* __restrict__ off,
                                              int2* __restrict__ epair) {
  __shared__ int cur[SBK];
  __shared__ int endi[SBK];
  __shared__ int wtot[4];
  int t = threadIdx.x, b = blockIdx.x;
  int n0 = b * SBK + t * 2, n1 = n0 + 1;
  int c0r = (n0 < NN) ? hist[n0] : 0;
  int c1r = (n1 < NN) ? hist[n1] : 0;
  int c0 = (c0r + (PAD - 1)) & ~(PAD - 1);
  int c1 = (c1r + (PAD - 1)) & ~(PAD - 1);
  int sum2 = c0 + c1;
  int lane = t & 63, wv = t >> 6;
  int inc = sum2;
  for (int d = 1; d < 64; d <<= 1) { int tt = __shfl_up(inc, d, 64); if (lane >= d) inc += tt; }
  if (lane == 63) wtot[wv] = inc;
  __syncthreads();
  int wbase = 0;
#pragma unroll
  for (int k = 0; k < 4; ++k) if (k < wv) wbase += wtot[k];
  int base0 = obase[b] + wbase + (inc - sum2);
  int base1 = base0 + c0;
  if (n0 < NN) off[n0] = base0;
  if (n1 < NN) off[n1] = base1;
  cur[t * 2]     = base0;
  cur[t * 2 + 1] = base1;
  endi[t * 2]     = base0 + c0;
  endi[t * 2 + 1] = base1 + c1;
  __syncthreads();
  int s = b * CAP, e = bcur[b];
  for (int j = s + t; j < e; j += 256) {
    uint2 u = coarse[j];
    int dlo = u.x >> 17;
    int src = u.x & 0x1FFFF;
    int pos = atomicAdd(&cur[dlo], 1);
    epair[pos] = make_int2(src, (int)u.y);
  }
  __syncthreads();
#pragma unroll
  for (int h = 0; h < 2; ++h) {
    int i = t * 2 + h;
    for (int p = cur[i]; p < endi[i]; ++p) epair[p] = make_int2(0, 0);
  }
}

// sup = bf16( dinv[:,None] * (x @ W) ) ; W (32KB) staged in LDS.
__global__ __launch_bounds__(256) void k_gemm(const float* __restrict__ x,
                                              const float* __restrict__ W,
                                              const float* __restrict__ dinv,
                                              u16* __restrict__ supb) {
  __shared__ float4 Wl[NF * NH / 4];
  const float4* Wg = (const float4*)W;
  for (int i = threadIdx.x; i < NF * NH / 4; i += 256) Wl[i] = Wg[i];
  __syncthreads();
  int lane16 = threadIdx.x & 15;
  int rowin  = threadIdx.x >> 4;
  const float4* x4 = (const float4*)x;
  int rowbase = blockIdx.x * 128;
  for (int r0 = 0; r0 < 128; r0 += 16) {
    int r = rowbase + r0 + rowin;
    if (r >= NN) return;
    float4 acc = make_float4(0.f, 0.f, 0.f, 0.f);
#pragma unroll 8
    for (int kk = 0; kk < NF / 4; ++kk) {
      float4 xv = x4[r * (NF / 4) + kk];
      float4 w0 = Wl[(4 * kk + 0) * 16 + lane16];
      float4 w1 = Wl[(4 * kk + 1) * 16 + lane16];
      float4 w2 = Wl[(4 * kk + 2) * 16 + lane16];
      float4 w3 = Wl[(4 * kk + 3) * 16 + lane16];
      acc.x += xv.x * w0.x + xv.y * w1.x + xv.z * w2.x + xv.w * w3.x;
      acc.y += xv.x * w0.y + xv.y * w1.y + xv.z * w2.y + xv.w * w3.y;
      acc.z += xv.x * w0.z + xv.y * w1.z + xv.z * w2.z + xv.w * w3.z;
      acc.w += xv.x * w0.w + xv.y * w1.w + xv.z * w2.w + xv.w * w3.w;
    }
    float di = dinv[r];
    ushort4 o;
    o.x = f2bf(acc.x * di); o.y = f2bf(acc.y * di);
    o.z = f2bf(acc.z * di); o.w = f2bf(acc.w * di);
    *(ushort4*)&supb[(size_t)r * NH + lane16 * 4] = o;
  }
}

// One wave per node: padded segment-reduce (8 gathers in flight, u32 saddr
// offsets, int4 edge loads), then LDS-transpose Student-t head.
__global__ __launch_bounds__(256) void k_agg_q(const int2* __restrict__ epair,
                                               const int* __restrict__ off,
                                               const float* __restrict__ dinv,
                                               const u16* __restrict__ supb,
                                               const float* __restrict__ b,
                                               const float* __restrict__ mu,
                                               float* __restrict__ z,
                                               float* __restrict__ q) {
  __shared__ float muL[NK * 68];    // padded rows break bank aliasing
  __shared__ float zsh[4][64];
  for (int i = threadIdx.x; i < NK * NH; i += 256) muL[(i >> 6) * 68 + (i & 63)] = mu[i];
  __syncthreads();
  int wid  = (blockIdx.x * 256 + threadIdx.x) >> 6;  // node
  int lane = threadIdx.x & 63;                       // feature
  int wv   = threadIdx.x >> 6;

  int startU = __builtin_amdgcn_readfirstlane(off[wid]);
  int endU   = __builtin_amdgcn_readfirstlane(off[wid + 1]);
  float di  = dinv[wid];
  u32 loff = (u32)lane << 1;
  float acc0 = gath(supb, ((u32)wid << 7) + loff);   // self-loop term
  float acc1 = 0.f;

  for (int j = startU; j < endU; j += 8) {
    int4 p01 = *(const int4*)&epair[j + 0];
    int4 p23 = *(const int4*)&epair[j + 2];
    int4 p45 = *(const int4*)&epair[j + 4];
    int4 p67 = *(const int4*)&epair[j + 6];
    float v0 = gath(supb, ((u32)p01.x << 7) + loff);
    float v1 = gath(supb, ((u32)p01.z << 7) + loff);
    float v2 = gath(supb, ((u32)p23.x << 7) + loff);
    float v3 = gath(supb, ((u32)p23.z << 7) + loff);
    float v4 = gath(supb, ((u32)p45.x << 7) + loff);
    float v5 = gath(supb, ((u32)p45.z << 7) + loff);
    float v6 = gath(supb, ((u32)p67.x << 7) + loff);
    float v7 = gath(supb, ((u32)p67.z << 7) + loff);
    acc0 += __int_as_float(p01.y) * v0;
    acc1 += __int_as_float(p01.w) * v1;
    acc0 += __int_as_float(p23.y) * v2;
    acc1 += __int_as_float(p23.w) * v3;
    acc0 += __int_as_float(p45.y) * v4;
    acc1 += __int_as_float(p45.w) * v5;
    acc0 += __int_as_float(p67.y) * v6;
    acc1 += __int_as_float(p67.w) * v7;
  }

  float zz = di * (acc0 + acc1) + b[lane];
  z[(size_t)wid * NH + lane] = zz;
  zsh[wv][lane] = zz;   // same-wave write->read

  float qv = 0.f;
  if (lane < NK) {
    const float4* zr = (const float4*)zsh[wv];          // broadcast reads
    const float4* mr = (const float4*)&muL[lane * 68];  // per-lane mu row
    float s0 = 0.f, s1 = 0.f, s2 = 0.f, s3 = 0.f;
#pragma unroll
    for (int j = 0; j < 16; ++j) {
      float4 zv = zr[j];
      float4 mv = mr[j];
      float a0 = zv.x - mv.x, a1 = zv.y - mv.y, a2 = zv.z - mv.z, a3 = zv.w - mv.w;
      s0 += a0 * a0; s1 += a1 * a1; s2 += a2 * a2; s3 += a3 * a3;
    }
    float d2 = (s0 + s1) + (s2 + s3);
    float tq = 1.0f / (1.0f + d2 * (1.0f / ALPHA) + 1e-8f);
    qv = exp2f((ALPHA + 1.0f) * __log2f(tq));   // /2 cancels in normalization
  }
  float ssum = qv;
  for (int o = 32; o; o >>= 1) ssum += __shfl_xor(ssum, o, 64);
  if (lane < NK) q[(size_t)wid * NK + lane] = qv / ssum;
}

extern "C" void kernel_launch(void* const* d_in, const int* in_sizes, int n_in,
                              void* d_out, int out_size, void* d_ws, size_t ws_size,
                              hipStream_t stream) {
  const float* x  = (const float*)d_in[0];
  const void*  ei = d_in[1];
  const float* w  = (const float*)d_in[2];
  const float* W  = (const float*)d_in[3];
  const float* b  = (const float*)d_in[4];
  const float* mu = (const float*)d_in[5];

  char* ws = (char*)d_ws;
  int*   flag   = (int*)(ws + O_FLAG);
  float* dinv   = (float*)(ws + O_DINV);
  int*   hist   = (int*)(ws + O_HIST);
  int*   off    = (int*)(ws + O_OFF);
  int*   bcur   = (int*)(ws + O_BCUR);
  int*   bsum   = (int*)(ws + O_BSUM);
  int*   obase  = (int*)(ws + O_OBASE);
  uint2* coarse = (uint2*)(ws + O_COARSE);
  int2*  epair  = (int2*)(ws + O_EPAIR);
  u16*   supb   = (u16*)(ws + O_SUP);

  float* z = (float*)d_out;
  float* q = (float*)d_out + (size_t)NN * NH;

  hipLaunchKernelGGL(k_detect, dim3(1),                   dim3(256), 0, stream, ei, flag, bcur);
  hipLaunchKernelGGL(k_coarse, dim3((NE + CT - 1) / CT),  dim3(256), 0, stream, ei, flag, w, bcur, coarse);
  hipLaunchKernelGGL(k_nhist,  dim3(NSB),                 dim3(256), 0, stream, coarse, bcur, hist, dinv, bsum);
  hipLaunchKernelGGL(k_bscan2, dim3(1),                   dim3(256), 0, stream, bsum, obase, off);
  hipLaunchKernelGGL(k_fine,   dim3(NSB),                 dim3(256), 0, stream, coarse, bcur, obase, hist, off, epair);
  hipLaunchKernelGGL(k_gemm,   dim3((NN + 127) / 128),    dim3(256), 0, stream, x, W, dinv, supb);
  hipLaunchKernelGGL(k_agg_q,  dim3((NN * 64) / 256),     dim3(256), 0, stream, epair, off, dinv, supb, b, mu, z, q);
}